// Round 1
// baseline (267.458 us; speedup 1.0000x reference)
//
#include <hip/hip_runtime.h>

#define N_NODES   20000
#define N_ANCHORS 64
#define D         128
#define N_EDGES   (N_NODES * N_ANCHORS)

// ---------------- Kernel 1: u_feat = feature@Wu + bu ; v_feat = feature@Wv + bv
// 256 threads, 16 nodes per block. Thread: j = tid&127 (output col), g = tid>>7
// (node half). Each thread computes 8 nodes x 1 col for BOTH u and v.
__global__ __launch_bounds__(256) void proj_kernel(
    const float* __restrict__ feature,
    const float* __restrict__ Wu, const float* __restrict__ bu,
    const float* __restrict__ Wv, const float* __restrict__ bv,
    float* __restrict__ u_feat, float* __restrict__ v_feat)
{
    __shared__ float f[16 * D];   // 8 KiB feature tile
    const int tid = threadIdx.x;
    const int n0  = blockIdx.x * 16;

    // stage 16x128 feature rows, coalesced float4
    {
        const float4* g4 = (const float4*)(feature + (size_t)n0 * D);
        float4* f4 = (float4*)f;
        f4[tid]       = g4[tid];
        f4[tid + 256] = g4[tid + 256];
    }
    __syncthreads();

    const int j = tid & 127;
    const int g = tid >> 7;          // 0 or 1 (wave-uniform)

    float accu[8], accv[8];
    const float buj = bu[j], bvj = bv[j];
    #pragma unroll
    for (int r = 0; r < 8; ++r) { accu[r] = buj; accv[r] = bvj; }

    #pragma unroll 4
    for (int k = 0; k < D; ++k) {
        const float wu = Wu[k * D + j];
        const float wv = Wv[k * D + j];
        #pragma unroll
        for (int r = 0; r < 8; ++r) {
            const float fr = f[(g * 8 + r) * D + k];   // wave-broadcast LDS read
            accu[r] = fmaf(fr, wu, accu[r]);
            accv[r] = fmaf(fr, wv, accv[r]);
        }
    }

    #pragma unroll
    for (int r = 0; r < 8; ++r) {
        const int n = n0 + g * 8 + r;
        u_feat[(size_t)n * D + j] = accu[r];
        v_feat[(size_t)n * D + j] = accv[r];
    }
}

// ---------------- Kernel 2: edge gather + relu + Wpos-dot + anchor-mean
// 256 threads = 4 waves; one wave per node. Wave processes 4 anchors per
// iteration: 16 lanes x 8 dims each (2x float4 row loads).
__global__ __launch_bounds__(256) void edge_kernel(
    const float* __restrict__ u_feat, const float* __restrict__ v_feat,
    const float* __restrict__ sp_dist, const int* __restrict__ src,
    const int* __restrict__ dst, const int* __restrict__ anchor_eid,
    const float* __restrict__ Wpos, const float* __restrict__ bpos,
    float* __restrict__ out_pos, float* __restrict__ out_struct)
{
    const int wave = threadIdx.x >> 6;       // 0..3
    const int lane = threadIdx.x & 63;
    const int n    = blockIdx.x * 4 + wave;  // grid is exact: 5000*4 = 20000

    const int sub = lane & 15;               // dim group: dims [sub*8, sub*8+8)
    const int grp = lane >> 4;               // anchor sub-slot 0..3

    // per-lane anchor metadata (lane a holds anchor a's indices)
    const int   e   = n * N_ANCHORS + lane;
    const int   eid = anchor_eid[e];
    const int   s   = src[eid];
    const int   d   = dst[eid];
    const float sp  = sp_dist[eid];

    // Wpos fragment for this lane's 8 dims
    const float4 wpA = ((const float4*)Wpos)[sub * 2];
    const float4 wpB = ((const float4*)Wpos)[sub * 2 + 1];

    float acc[8];
    #pragma unroll
    for (int k = 0; k < 8; ++k) acc[k] = 0.f;

    __shared__ float posbuf[4][N_ANCHORS];

    for (int it = 0; it < 16; ++it) {
        const int a = it * 4 + grp;          // this lane-group's anchor
        const int   sa  = __shfl(s,  a);
        const int   da  = __shfl(d,  a);
        const float spa = __shfl(sp, a);

        const float4* ur = (const float4*)(u_feat + (size_t)sa * D + sub * 8);
        const float4* vr = (const float4*)(v_feat + (size_t)da * D + sub * 8);
        const float4 u0 = ur[0], u1 = ur[1];
        const float4 v0 = vr[0], v1 = vr[1];

        float m[8];
        m[0] = fmaf(u0.x, spa, v0.x); m[1] = fmaf(u0.y, spa, v0.y);
        m[2] = fmaf(u0.z, spa, v0.z); m[3] = fmaf(u0.w, spa, v0.w);
        m[4] = fmaf(u1.x, spa, v1.x); m[5] = fmaf(u1.y, spa, v1.y);
        m[6] = fmaf(u1.z, spa, v1.z); m[7] = fmaf(u1.w, spa, v1.w);
        #pragma unroll
        for (int k = 0; k < 8; ++k) m[k] = fmaxf(m[k], 0.f);
        #pragma unroll
        for (int k = 0; k < 8; ++k) acc[k] += m[k];

        float p = m[0] * wpA.x + m[1] * wpA.y + m[2] * wpA.z + m[3] * wpA.w
                + m[4] * wpB.x + m[5] * wpB.y + m[6] * wpB.z + m[7] * wpB.w;
        // reduce over the 16 lanes of this anchor group
        p += __shfl_xor(p, 8);
        p += __shfl_xor(p, 4);
        p += __shfl_xor(p, 2);
        p += __shfl_xor(p, 1);
        if (sub == 0) posbuf[wave][a] = p;
    }

    // combine the 4 anchor-groups' structure partials (dims identical per sub)
    #pragma unroll
    for (int k = 0; k < 8; ++k) {
        acc[k] += __shfl_xor(acc[k], 16);
        acc[k] += __shfl_xor(acc[k], 32);
    }

    __syncthreads();   // posbuf visibility (each wave reads only its own row)

    const float bp = bpos[0];
    out_pos[(size_t)n * N_ANCHORS + lane] = posbuf[wave][lane] + bp;

    if (grp == 0) {
        const float inv = 1.0f / (float)N_ANCHORS;
        float4 o0, o1;
        o0.x = acc[0] * inv; o0.y = acc[1] * inv; o0.z = acc[2] * inv; o0.w = acc[3] * inv;
        o1.x = acc[4] * inv; o1.y = acc[5] * inv; o1.z = acc[6] * inv; o1.w = acc[7] * inv;
        float4* os = (float4*)(out_struct + (size_t)n * D + sub * 8);
        os[0] = o0;
        os[1] = o1;
    }
}

extern "C" void kernel_launch(void* const* d_in, const int* in_sizes, int n_in,
                              void* d_out, int out_size, void* d_ws, size_t ws_size,
                              hipStream_t stream) {
    const float* feature    = (const float*)d_in[0];
    const float* sp_dist    = (const float*)d_in[1];
    const float* Wu         = (const float*)d_in[2];
    const float* bu         = (const float*)d_in[3];
    const float* Wv         = (const float*)d_in[4];
    const float* bv         = (const float*)d_in[5];
    const float* Wpos       = (const float*)d_in[6];
    const float* bpos       = (const float*)d_in[7];
    const int*   src        = (const int*)d_in[8];
    const int*   dst        = (const int*)d_in[9];
    const int*   anchor_eid = (const int*)d_in[10];

    float* u_feat = (float*)d_ws;
    float* v_feat = u_feat + (size_t)N_NODES * D;

    float* out_pos    = (float*)d_out;                       // [20000*64]
    float* out_struct = out_pos + (size_t)N_EDGES;           // [20000*128]

    proj_kernel<<<N_NODES / 16, 256, 0, stream>>>(feature, Wu, bu, Wv, bv,
                                                  u_feat, v_feat);
    edge_kernel<<<N_NODES / 4, 256, 0, stream>>>(u_feat, v_feat, sp_dist, src,
                                                 dst, anchor_eid, Wpos, bpos,
                                                 out_pos, out_struct);
}

// Round 2
// 160.305 us; speedup vs baseline: 1.6684x; 1.6684x over previous
//
#include <hip/hip_runtime.h>

#define N_NODES   20000
#define N_ANCHORS 64
#define D         128
#define N_EDGES   (N_NODES * N_ANCHORS)

// ---- bf16 helpers (round-to-nearest-even pack, shift unpack) ----
static __device__ __forceinline__ unsigned short f32_to_bf16(float x) {
    unsigned int u = __float_as_uint(x);
    u += 0x7FFFu + ((u >> 16) & 1u);   // RNE
    return (unsigned short)(u >> 16);
}
static __device__ __forceinline__ float bf_lo(unsigned int w) {
    return __uint_as_float(w << 16);
}
static __device__ __forceinline__ float bf_hi(unsigned int w) {
    return __uint_as_float(w & 0xFFFF0000u);
}

// ---------------- Kernel 1: u/v projections, f32 compute, bf16 output
// 256 threads, 16 nodes per block. j = tid&127 (col), g = tid>>7 (node half).
// Each thread: 8 nodes x 1 col for both u and v. LDS reads are float4.
__global__ __launch_bounds__(256) void proj_kernel(
    const float* __restrict__ feature,
    const float* __restrict__ Wu, const float* __restrict__ bu,
    const float* __restrict__ Wv, const float* __restrict__ bv,
    unsigned short* __restrict__ u_bf, unsigned short* __restrict__ v_bf)
{
    __shared__ float f[16 * D];   // 8 KiB feature tile
    const int tid = threadIdx.x;
    const int n0  = blockIdx.x * 16;

    {
        const float4* g4 = (const float4*)(feature + (size_t)n0 * D);
        float4* f4 = (float4*)f;
        f4[tid]       = g4[tid];
        f4[tid + 256] = g4[tid + 256];
    }
    __syncthreads();

    const int j = tid & 127;
    const int g = tid >> 7;

    float accu[8], accv[8];
    const float buj = bu[j], bvj = bv[j];
    #pragma unroll
    for (int r = 0; r < 8; ++r) { accu[r] = buj; accv[r] = bvj; }

    for (int k = 0; k < D; k += 4) {
        const float wu0 = Wu[(k + 0) * D + j];
        const float wu1 = Wu[(k + 1) * D + j];
        const float wu2 = Wu[(k + 2) * D + j];
        const float wu3 = Wu[(k + 3) * D + j];
        const float wv0 = Wv[(k + 0) * D + j];
        const float wv1 = Wv[(k + 1) * D + j];
        const float wv2 = Wv[(k + 2) * D + j];
        const float wv3 = Wv[(k + 3) * D + j];
        #pragma unroll
        for (int r = 0; r < 8; ++r) {
            const float4 fr = *(const float4*)&f[(g * 8 + r) * D + k];
            accu[r] = fmaf(fr.x, wu0, accu[r]);
            accu[r] = fmaf(fr.y, wu1, accu[r]);
            accu[r] = fmaf(fr.z, wu2, accu[r]);
            accu[r] = fmaf(fr.w, wu3, accu[r]);
            accv[r] = fmaf(fr.x, wv0, accv[r]);
            accv[r] = fmaf(fr.y, wv1, accv[r]);
            accv[r] = fmaf(fr.z, wv2, accv[r]);
            accv[r] = fmaf(fr.w, wv3, accv[r]);
        }
    }

    #pragma unroll
    for (int r = 0; r < 8; ++r) {
        const int n = n0 + g * 8 + r;
        u_bf[(size_t)n * D + j] = f32_to_bf16(accu[r]);
        v_bf[(size_t)n * D + j] = f32_to_bf16(accv[r]);
    }
}

// ---------------- Kernel 2: edge gather (bf16 rows) + relu + Wpos-dot + mean
// 256 threads = 4 waves; one wave per node. 4 anchors/iter: 16 lanes x 8 dims.
__global__ __launch_bounds__(256) void edge_kernel(
    const unsigned short* __restrict__ u_bf, const unsigned short* __restrict__ v_bf,
    const float* __restrict__ sp_dist, const int* __restrict__ src,
    const int* __restrict__ dst, const int* __restrict__ anchor_eid,
    const float* __restrict__ Wpos, const float* __restrict__ bpos,
    float* __restrict__ out_pos, float* __restrict__ out_struct)
{
    const int wave = threadIdx.x >> 6;       // 0..3
    const int lane = threadIdx.x & 63;
    const int n    = blockIdx.x * 4 + wave;  // 5000*4 = 20000 exact

    const int sub = lane & 15;               // dims [sub*8, sub*8+8)
    const int grp = lane >> 4;               // anchor sub-slot 0..3

    const int   e   = n * N_ANCHORS + lane;
    const int   eid = anchor_eid[e];
    const int   s   = src[eid];
    const int   d   = dst[eid];
    const float sp  = sp_dist[eid];

    const float4 wpA = ((const float4*)Wpos)[sub * 2];
    const float4 wpB = ((const float4*)Wpos)[sub * 2 + 1];

    float acc[8];
    #pragma unroll
    for (int k = 0; k < 8; ++k) acc[k] = 0.f;

    __shared__ float posbuf[4][N_ANCHORS];

    for (int it = 0; it < 16; ++it) {
        const int a = it * 4 + grp;
        const int   sa  = __shfl(s,  a);
        const int   da  = __shfl(d,  a);
        const float spa = __shfl(sp, a);

        const uint4 uu = *(const uint4*)(u_bf + (size_t)sa * D + sub * 8);
        const uint4 vv = *(const uint4*)(v_bf + (size_t)da * D + sub * 8);

        float m[8];
        m[0] = fmaf(bf_lo(uu.x), spa, bf_lo(vv.x));
        m[1] = fmaf(bf_hi(uu.x), spa, bf_hi(vv.x));
        m[2] = fmaf(bf_lo(uu.y), spa, bf_lo(vv.y));
        m[3] = fmaf(bf_hi(uu.y), spa, bf_hi(vv.y));
        m[4] = fmaf(bf_lo(uu.z), spa, bf_lo(vv.z));
        m[5] = fmaf(bf_hi(uu.z), spa, bf_hi(vv.z));
        m[6] = fmaf(bf_lo(uu.w), spa, bf_lo(vv.w));
        m[7] = fmaf(bf_hi(uu.w), spa, bf_hi(vv.w));
        #pragma unroll
        for (int k = 0; k < 8; ++k) m[k] = fmaxf(m[k], 0.f);
        #pragma unroll
        for (int k = 0; k < 8; ++k) acc[k] += m[k];

        float p = m[0] * wpA.x + m[1] * wpA.y + m[2] * wpA.z + m[3] * wpA.w
                + m[4] * wpB.x + m[5] * wpB.y + m[6] * wpB.z + m[7] * wpB.w;
        p += __shfl_xor(p, 8);
        p += __shfl_xor(p, 4);
        p += __shfl_xor(p, 2);
        p += __shfl_xor(p, 1);
        if (sub == 0) posbuf[wave][a] = p;
    }

    #pragma unroll
    for (int k = 0; k < 8; ++k) {
        acc[k] += __shfl_xor(acc[k], 16);
        acc[k] += __shfl_xor(acc[k], 32);
    }

    __syncthreads();

    const float bp = bpos[0];
    out_pos[(size_t)n * N_ANCHORS + lane] = posbuf[wave][lane] + bp;

    if (grp == 0) {
        const float inv = 1.0f / (float)N_ANCHORS;
        float4 o0, o1;
        o0.x = acc[0] * inv; o0.y = acc[1] * inv; o0.z = acc[2] * inv; o0.w = acc[3] * inv;
        o1.x = acc[4] * inv; o1.y = acc[5] * inv; o1.z = acc[6] * inv; o1.w = acc[7] * inv;
        float4* os = (float4*)(out_struct + (size_t)n * D + sub * 8);
        os[0] = o0;
        os[1] = o1;
    }
}

extern "C" void kernel_launch(void* const* d_in, const int* in_sizes, int n_in,
                              void* d_out, int out_size, void* d_ws, size_t ws_size,
                              hipStream_t stream) {
    const float* feature    = (const float*)d_in[0];
    const float* sp_dist    = (const float*)d_in[1];
    const float* Wu         = (const float*)d_in[2];
    const float* bu         = (const float*)d_in[3];
    const float* Wv         = (const float*)d_in[4];
    const float* bv         = (const float*)d_in[5];
    const float* Wpos       = (const float*)d_in[6];
    const float* bpos       = (const float*)d_in[7];
    const int*   src        = (const int*)d_in[8];
    const int*   dst        = (const int*)d_in[9];
    const int*   anchor_eid = (const int*)d_in[10];

    unsigned short* u_bf = (unsigned short*)d_ws;
    unsigned short* v_bf = u_bf + (size_t)N_NODES * D;

    float* out_pos    = (float*)d_out;
    float* out_struct = out_pos + (size_t)N_EDGES;

    proj_kernel<<<N_NODES / 16, 256, 0, stream>>>(feature, Wu, bu, Wv, bv,
                                                  u_bf, v_bf);
    edge_kernel<<<N_NODES / 4, 256, 0, stream>>>(u_bf, v_bf, sp_dist, src,
                                                 dst, anchor_eid, Wpos, bpos,
                                                 out_pos, out_struct);
}